// Round 2
// baseline (335.137 us; speedup 1.0000x reference)
//
#include <hip/hip_runtime.h>
#include <hip/hip_cooperative_groups.h>

namespace cg = cooperative_groups;

#define NM_ 1500000
#define NT_ 100000
#define NF_ 1500000
#define NTOT (NM_ + NT_ + NF_)
#define NBY_ 1024
#define TDv 0.9f

#define FB_  512          /* fused grid blocks (cooperative: 2/CU x 256 CU) */
#define FT_  1024         /* fused threads/block */
#define NIT  6            /* nodes cached per thread: 6*512*1024 >= NTOT */
#define SHY_ 4
#define TSY_ 16
#define NTILY_ 64                 /* y-tiles */
#define NTILES_ 2048              /* 32 x-tiles x 64 y-tiles (32x16 bins) */
#define CAP_M 2048u               /* movable bucket stride (mean 1619, +10 sigma) */
#define CAP_F 256u                /* fixed-rect bucket stride (mean ~115, +13 sigma) */
#define QS 0.0009765625f          /* 1/1024 */
#define FXS 65536.0f              /* LDS fixed-point scale (2^16) */
#define FXSI 1.52587890625e-5f    /* 2^-16 */

// universal 8B item: tile-local fixed point
// w0 = xq(u6.10)<<16 | yq(u6.10)   (coords offset by +32; range [-32,32))
// w1 = sxq(u5.10)<<16 | syq(u5.10) (sizes up to 20.03 fit 15 bits)
__device__ inline uint2 pack_item(float xl, float yl, float sx, float sy) {
    unsigned xq = min((unsigned)__builtin_rintf((xl + 32.0f) * 1024.0f), 65535u);
    unsigned yq = min((unsigned)__builtin_rintf((yl + 32.0f) * 1024.0f), 65535u);
    unsigned sxq = (unsigned)__builtin_rintf(sx * 1024.0f);
    unsigned syq = (unsigned)__builtin_rintf(sy * 1024.0f);
    uint2 r; r.x = (xq << 16) | yq; r.y = (sxq << 16) | syq; return r;
}

// movable item: fully-unrolled 3x3 (span <= 3x3 always); zero-weight adds
// predicated off (typical footprint 2x2 -> ~5/9 adds are zero).
__device__ inline void mov_3x3(uint2 v, unsigned* sm) {
    float xl = (float)(v.x >> 16) * QS - 32.0f;
    float yl = (float)(v.x & 0xffffu) * QS - 32.0f;
    float sx = (float)(v.y >> 16) * QS;
    float sy = (float)(v.y & 0xffffu) * QS;
    float xh = xl + sx, yh = yl + sy;
    int bx0 = (int)floorf(xl), by0 = (int)floorf(yl);
    #pragma unroll
    for (int dx = 0; dx < 3; ++dx) {
        int bx = bx0 + dx;
        float ox = fmaxf(fminf(xh, (float)(bx + 1)) - fmaxf(xl, (float)bx), 0.0f) * FXS;
        bool okx = ((unsigned)bx < 32u);
        int bxc = min(max(bx, 0), 31);
        #pragma unroll
        for (int dy = 0; dy < 3; ++dy) {
            int by = by0 + dy;
            float oy = fmaxf(fminf(yh, (float)(by + 1)) - fmaxf(yl, (float)by), 0.0f);
            float w = (okx && ((unsigned)by < 16u)) ? ox * oy : 0.0f;
            int byc = min(max(by, 0), 15);
            if (w != 0.0f)
                atomicAdd(&sm[(bxc << 4) + byc], (unsigned)__float2uint_rn(w));
        }
    }
}

// fixed rect via separable difference maps: <=16 point adds instead of
// walking the O(area) footprint. Signed entries ride in u32 two's-complement.
// A zero item (all fields 0) is a no-op (all predicates false).
__device__ inline void fix_rect_diff(uint2 v, unsigned* S, unsigned* U,
                                     unsigned* V, unsigned* W) {
    float xl = (float)(v.x >> 16) * QS - 32.0f;
    float yl = (float)(v.x & 0xffffu) * QS - 32.0f;
    float sx = (float)(v.y >> 16) * QS;
    float sy = (float)(v.y & 0xffffu) * QS;
    float xh = xl + sx, yh = yl + sy;
    int xlo = (int)floorf(xl), xhi = (int)floorf(xh);
    int ylo = (int)floorf(yl), yhi = (int)floorf(yh);
    float ax = fminf(xh, (float)(xlo + 1)) - xl;
    float bx = xh - (float)xhi;
    float ay = fminf(yh, (float)(ylo + 1)) - yl;
    float by = yh - (float)yhi;
    int xs = max(xlo + 1, 0), xe = min(xhi - 1, 31);
    int ys = max(ylo + 1, 0), ye = min(yhi - 1, 15);
    bool runx = (xs <= xe), runy = (ys <= ye);
    bool c_xlo = ((unsigned)xlo < 32u), c_xhi = ((unsigned)xhi < 32u);
    bool c_ylo = ((unsigned)ylo < 16u), c_yhi = ((unsigned)yhi < 16u);
    const float SC = TDv * FXS;
    if (c_xlo && c_ylo) atomicAdd(&S[(xlo << 4) + ylo], (unsigned)__float2int_rn(ax * ay * SC));
    if (c_xlo && c_yhi) atomicAdd(&S[(xlo << 4) + yhi], (unsigned)__float2int_rn(ax * by * SC));
    if (c_xhi && c_ylo) atomicAdd(&S[(xhi << 4) + ylo], (unsigned)__float2int_rn(bx * ay * SC));
    if (c_xhi && c_yhi) atomicAdd(&S[(xhi << 4) + yhi], (unsigned)__float2int_rn(bx * by * SC));
    if (runy) {
        int iax = __float2int_rn(ax * SC), ibx = __float2int_rn(bx * SC);
        if (c_xlo) {
            atomicAdd(&U[(xlo << 4) + ys], (unsigned)iax);
            if (ye < 15) atomicAdd(&U[(xlo << 4) + ye + 1], (unsigned)(-iax));
        }
        if (c_xhi) {
            atomicAdd(&U[(xhi << 4) + ys], (unsigned)ibx);
            if (ye < 15) atomicAdd(&U[(xhi << 4) + ye + 1], (unsigned)(-ibx));
        }
    }
    if (runx) {
        int iay = __float2int_rn(ay * SC), iby = __float2int_rn(by * SC);
        if (c_ylo) {
            atomicAdd(&V[(xs << 4) + ylo], (unsigned)iay);
            if (xe < 31) atomicAdd(&V[((xe + 1) << 4) + ylo], (unsigned)(-iay));
        }
        if (c_yhi) {
            atomicAdd(&V[(xs << 4) + yhi], (unsigned)iby);
            if (xe < 31) atomicAdd(&V[((xe + 1) << 4) + yhi], (unsigned)(-iby));
        }
    }
    if (runx && runy) {
        const int iSC = 58982;   /* round(TDv * FXS) */
        atomicAdd(&W[(xs << 4) + ys], (unsigned)iSC);
        if (ye < 15) atomicAdd(&W[(xs << 4) + ye + 1], (unsigned)(-iSC));
        if (xe < 31) {
            atomicAdd(&W[((xe + 1) << 4) + ys], (unsigned)(-iSC));
            if (ye < 15) atomicAdd(&W[((xe + 1) << 4) + ye + 1], (unsigned)iSC);
        }
    }
}

// ==================== fused cooperative kernel ====================
// One node replaces {memset out, memset gM, bin_k, accum2_k}:
//   zero gM/gF + LDS hist -> grid.sync -> bump+emit -> grid.sync ->
//   per-tile accum (4 tile-groups of 256 thr per block) -> partials ->
//   grid.sync -> block-0 final reduce -> plain stores to out.
// LDS: 32KB shm union (phase1: lhM/lhF/cM/cF; phase2: 4x{sm,U,V,W}).
// __launch_bounds__(1024,8) caps VGPR at 64 -> 2 blocks/CU co-resident.
__global__ __launch_bounds__(FT_, 8) void
fused_k(const float* __restrict__ xs, const float* __restrict__ ys,
        const float* __restrict__ sxs, const float* __restrict__ sys,
        unsigned* __restrict__ gM, unsigned* __restrict__ gF,
        uint2* __restrict__ itemsM, uint2* __restrict__ itemsF,
        const unsigned char* __restrict__ pm, float* __restrict__ partials,
        float* __restrict__ out) {
    cg::grid_group grid = cg::this_grid();
    __shared__ unsigned shm[8192];
    __shared__ float redS[16], redM[16];

    // ---------------- phase 1: binning ----------------
    unsigned* lhM = shm;
    unsigned* lhF = shm + 2048;
    unsigned* cM  = shm + 4096;
    unsigned* cF  = shm + 6144;
    for (int j = threadIdx.x; j < NTILES_; j += FT_) { lhM[j] = 0u; lhF[j] = 0u; }
    if (threadIdx.x < NTILES_ / FB_) {          // in-kernel counter zeroing
        gM[blockIdx.x * (NTILES_ / FB_) + threadIdx.x] = 0u;
        gF[blockIdx.x * (NTILES_ / FB_) + threadIdx.x] = 0u;
    }
    __syncthreads();
    int t0 = blockIdx.x * FT_ + threadIdx.x;
    float cx[NIT], cy[NIT], csx[NIT], csy[NIT];
    bool val[NIT], fixc[NIT];
    #pragma unroll
    for (int k = 0; k < NIT; ++k) {
        int i = t0 + k * (FB_ * FT_);
        val[k] = (i < NTOT);
        int ii = val[k] ? i : 0;
        cx[k] = xs[ii]; cy[k] = ys[ii]; csx[k] = sxs[ii]; csy[k] = sys[ii];
        fixc[k] = (i >= NM_) && (i < NM_ + NT_);
    }
    #pragma unroll
    for (int k = 0; k < NIT; ++k) if (val[k]) {
        float xi = cx[k], yi = cy[k];
        int txa = (int)xi >> 5, txb = (int)(xi + csx[k]) >> 5;
        int tya = (int)yi >> SHY_, tyb = (int)(yi + csy[k]) >> SHY_;
        unsigned* lh = fixc[k] ? lhF : lhM;
        for (int tx = txa; tx <= txb; ++tx)
            for (int ty = tya; ty <= tyb; ++ty) atomicAdd(&lh[tx * NTILY_ + ty], 1u);
    }
    __syncthreads();
    grid.sync();    // all gM/gF zeros + this block's histogram complete
    for (int j = threadIdx.x; j < NTILES_; j += FT_) {
        unsigned c = lhM[j];
        lhM[j] = c ? atomicAdd(&gM[j], c) : 0u;
        cM[j] = 0u;
        c = lhF[j];
        lhF[j] = c ? atomicAdd(&gF[j], c) : 0u;
        cF[j] = 0u;
    }
    __syncthreads();
    #pragma unroll
    for (int k = 0; k < NIT; ++k) if (val[k]) {
        float xi = cx[k], yi = cy[k], sxi = csx[k], syi = csy[k];
        int txa = (int)xi >> 5, txb = (int)(xi + sxi) >> 5;
        int tya = (int)yi >> SHY_, tyb = (int)(yi + syi) >> SHY_;
        if (fixc[k]) {
            for (int tx = txa; tx <= txb; ++tx)
                for (int ty = tya; ty <= tyb; ++ty) {
                    int tl = tx * NTILY_ + ty;
                    unsigned r = lhF[tl] + atomicAdd(&cF[tl], 1u);
                    if (r < CAP_F)
                        itemsF[(size_t)tl * CAP_F + r] =
                            pack_item(xi - (float)(tx * 32), yi - (float)(ty * TSY_), sxi, syi);
                }
        } else {
            for (int tx = txa; tx <= txb; ++tx)
                for (int ty = tya; ty <= tyb; ++ty) {
                    int tl = tx * NTILY_ + ty;
                    unsigned r = lhM[tl] + atomicAdd(&cM[tl], 1u);
                    if (r < CAP_M)
                        itemsM[(size_t)tl * CAP_M + r] =
                            pack_item(xi - (float)(tx * 32), yi - (float)(ty * TSY_), sxi, syi);
                }
        }
    }
    grid.sync();    // all items + counters visible device-wide

    // ---------------- phase 2: per-tile accumulation ----------------
    int g = threadIdx.x >> 8, tid = threadIdx.x & 255;
    int t = (blockIdx.x << 2) + g;
    unsigned* base = shm + (g << 11);
    unsigned* sm = base;
    unsigned* U  = base + 512;
    unsigned* V  = base + 1024;
    unsigned* W  = base + 1536;
    int baseX = (t >> 6) * 32, baseY = (t & 63) * TSY_;
    unsigned nm = min(gM[t], CAP_M), nf = min(gF[t], CAP_F);
    const uint2* im = itemsM + (size_t)t * CAP_M;
    const uint2* fi = itemsF + (size_t)t * CAP_F;

    uint2 itv[8];
    #pragma unroll
    for (int j = 0; j < 4; ++j) {
        unsigned k = tid * 2u + (unsigned)j * 512u;
        uint4 u = make_uint4(0u, 0u, 0u, 0u);
        if (k < nm) u = *(const uint4*)(im + k);     // 16B aligned
        bool h2 = (k + 1u < nm);
        itv[2 * j].x = u.x;           itv[2 * j].y = u.y;
        itv[2 * j + 1].x = h2 ? u.z : 0u;
        itv[2 * j + 1].y = h2 ? u.w : 0u;
    }
    uint2 fv = make_uint2(0u, 0u);
    if ((unsigned)tid < nf) fv = fi[tid];
    int j0 = tid, j1 = tid + 256;
    unsigned char p0 = pm[(size_t)(baseX + (j0 >> SHY_)) * NBY_ + baseY + (j0 & (TSY_ - 1))];
    unsigned char p1 = pm[(size_t)(baseX + (j1 >> SHY_)) * NBY_ + baseY + (j1 & (TSY_ - 1))];

    for (int j = threadIdx.x; j < 8192; j += FT_) shm[j] = 0u;
    __syncthreads();

    #pragma unroll
    for (int j = 0; j < 8; ++j) mov_3x3(itv[j], sm);
    fix_rect_diff(fv, sm, U, V, W);
    __syncthreads();

    if (tid < 32) {         // pass 1: per-bx prefix along y (per tile-group)
        int bx = tid;
        unsigned u = 0, w = 0;
        for (int by = 0; by < 16; ++by) {
            int idx = (bx << 4) + by;
            u += U[idx]; w += W[idx];
            sm[idx] += u;
            V[idx] += w;
        }
    }
    __syncthreads();
    if (tid < 16) {         // pass 2: per-by prefix along x
        int by = tid;
        unsigned tacc = 0;
        for (int bx = 0; bx < 32; ++bx) {
            int idx = (bx << 4) + by;
            tacc += V[idx];
            sm[idx] += tacc;
        }
    }
    __syncthreads();

    // reduce: 2 bins/thread within the group's tile
    float d0 = (float)sm[j0] * FXSI;
    if (p0) d0 = TDv;
    float d1 = (float)sm[j1] * FXSI;
    if (p1) d1 = TDv;
    float acc = fmaxf(d0 - TDv, 0.0f) + fmaxf(d1 - TDv, 0.0f);
    float mx = fmaxf(d0, d1);
    int lane = threadIdx.x & 63, wv = threadIdx.x >> 6;
    for (int off2 = 32; off2 > 0; off2 >>= 1) {
        acc += __shfl_down(acc, off2, 64);
        mx = fmaxf(mx, __shfl_down(mx, off2, 64));
    }
    if (lane == 0) { redS[wv] = acc; redM[wv] = mx; }
    __syncthreads();
    if (threadIdx.x == 0) {
        float S = redS[0], M = redM[0];
        for (int w2 = 1; w2 < 16; ++w2) { S += redS[w2]; M = fmaxf(M, redM[w2]); }
        partials[2 * blockIdx.x] = S;        // plain stores: no atomics, no memset
        partials[2 * blockIdx.x + 1] = M;
    }
    grid.sync();

    // ---------------- phase 3: final reduce (block 0) ----------------
    if (blockIdx.x == 0) {
        float S = 0.0f, M = 0.0f;
        if (threadIdx.x < FB_) {
            S = partials[2 * threadIdx.x];
            M = partials[2 * threadIdx.x + 1];
        }
        for (int off2 = 32; off2 > 0; off2 >>= 1) {
            S += __shfl_down(S, off2, 64);
            M = fmaxf(M, __shfl_down(M, off2, 64));
        }
        if (lane == 0) { redS[wv] = S; redM[wv] = M; }
        __syncthreads();
        if (threadIdx.x == 0) {
            float S2 = redS[0], M2 = redM[0];
            for (int w2 = 1; w2 < 16; ++w2) { S2 += redS[w2]; M2 = fmaxf(M2, redM[w2]); }
            out[0] = S2;            // density_cost
            out[1] = M2;            // max_density (bin_area = 1)
        }
    }
}

// ==================== fallback path (non-cooperative) ====================
#define NB_  512
#define BT_  1024

__device__ inline void tile_reduce(const unsigned* sm, const unsigned char* pmp,
                                   int baseX, int baseY, float* out) {
    float acc = 0.0f, mx = 0.0f;
    for (int j = threadIdx.x; j < 32 * TSY_; j += 256) {
        int lx = j >> SHY_, ly = j & (TSY_ - 1);
        float d = (float)sm[j] * FXSI;
        if (pmp[(size_t)(baseX + lx) * NBY_ + baseY + ly]) d = TDv;
        acc += fmaxf(d - TDv, 0.0f);
        mx = fmaxf(mx, d);
    }
    int lane = threadIdx.x & 63, wv = threadIdx.x >> 6;
    for (int off2 = 32; off2 > 0; off2 >>= 1) {
        acc += __shfl_down(acc, off2, 64);
        mx = fmaxf(mx, __shfl_down(mx, off2, 64));
    }
    __shared__ float ssum[4], smax[4];
    if (lane == 0) { ssum[wv] = acc; smax[wv] = mx; }
    __syncthreads();
    if (threadIdx.x == 0) {
        float S = ssum[0], M = smax[0];
        for (int w2 = 1; w2 < 4; ++w2) { S += ssum[w2]; M = fmaxf(M, smax[w2]); }
        atomicAdd(out, S);
        atomicMax((int*)out + 1, __float_as_int(M));
    }
}

__global__ __launch_bounds__(BT_) void
bin_k(const float* __restrict__ xs, const float* __restrict__ ys,
      const float* __restrict__ sxs, const float* __restrict__ sys,
      unsigned* __restrict__ gM, unsigned* __restrict__ gF,
      uint2* __restrict__ itemsM, uint2* __restrict__ itemsF) {
    __shared__ unsigned lhM[NTILES_], lhF[NTILES_];
    __shared__ unsigned cM[NTILES_], cF[NTILES_];
    for (int j = threadIdx.x; j < NTILES_; j += BT_) { lhM[j] = 0u; lhF[j] = 0u; }
    __syncthreads();
    int t0 = blockIdx.x * BT_ + threadIdx.x;
    float cx[NIT], cy[NIT], csx[NIT], csy[NIT];
    bool val[NIT], fixc[NIT];
    #pragma unroll
    for (int k = 0; k < NIT; ++k) {
        int i = t0 + k * (NB_ * BT_);
        val[k] = (i < NTOT);
        int ii = val[k] ? i : 0;
        cx[k] = xs[ii]; cy[k] = ys[ii]; csx[k] = sxs[ii]; csy[k] = sys[ii];
        fixc[k] = (i >= NM_) && (i < NM_ + NT_);
    }
    #pragma unroll
    for (int k = 0; k < NIT; ++k) if (val[k]) {
        float xi = cx[k], yi = cy[k];
        int txa = (int)xi >> 5, txb = (int)(xi + csx[k]) >> 5;
        int tya = (int)yi >> SHY_, tyb = (int)(yi + csy[k]) >> SHY_;
        unsigned* lh = fixc[k] ? lhF : lhM;
        for (int tx = txa; tx <= txb; ++tx)
            for (int ty = tya; ty <= tyb; ++ty) atomicAdd(&lh[tx * NTILY_ + ty], 1u);
    }
    __syncthreads();
    for (int j = threadIdx.x; j < NTILES_; j += BT_) {
        unsigned c = lhM[j];
        lhM[j] = c ? atomicAdd(&gM[j], c) : 0u;
        cM[j] = 0u;
        c = lhF[j];
        lhF[j] = c ? atomicAdd(&gF[j], c) : 0u;
        cF[j] = 0u;
    }
    __syncthreads();
    #pragma unroll
    for (int k = 0; k < NIT; ++k) if (val[k]) {
        float xi = cx[k], yi = cy[k], sxi = csx[k], syi = csy[k];
        int txa = (int)xi >> 5, txb = (int)(xi + sxi) >> 5;
        int tya = (int)yi >> SHY_, tyb = (int)(yi + syi) >> SHY_;
        if (fixc[k]) {
            for (int tx = txa; tx <= txb; ++tx)
                for (int ty = tya; ty <= tyb; ++ty) {
                    int tl = tx * NTILY_ + ty;
                    unsigned r = lhF[tl] + atomicAdd(&cF[tl], 1u);
                    if (r < CAP_F)
                        itemsF[(size_t)tl * CAP_F + r] =
                            pack_item(xi - (float)(tx * 32), yi - (float)(ty * TSY_), sxi, syi);
                }
        } else {
            for (int tx = txa; tx <= txb; ++tx)
                for (int ty = tya; ty <= tyb; ++ty) {
                    int tl = tx * NTILY_ + ty;
                    unsigned r = lhM[tl] + atomicAdd(&cM[tl], 1u);
                    if (r < CAP_M)
                        itemsM[(size_t)tl * CAP_M + r] =
                            pack_item(xi - (float)(tx * 32), yi - (float)(ty * TSY_), sxi, syi);
                }
        }
    }
}

__global__ __launch_bounds__(256) void
accum2_k(const unsigned* __restrict__ gM, const unsigned* __restrict__ gF,
         const uint2* __restrict__ itemsM, const uint2* __restrict__ itemsF,
         const unsigned char* __restrict__ pm, float* __restrict__ out) {
    __shared__ unsigned sm[512], U[512], V[512], W[512];
    int t = blockIdx.x;
    int baseX = (t >> 6) * 32, baseY = (t & 63) * TSY_;
    for (int j = threadIdx.x; j < 512; j += 256) { sm[j] = 0u; U[j] = 0u; V[j] = 0u; W[j] = 0u; }
    __syncthreads();
    unsigned nm = min(gM[t], CAP_M), nf = min(gF[t], CAP_F);
    const uint2* im = itemsM + (size_t)t * CAP_M;
    const uint2* fi = itemsF + (size_t)t * CAP_F;
    for (unsigned k = threadIdx.x * 2; k < nm; k += 512) {
        uint2 v0 = im[k];
        bool h2 = (k + 1 < nm);
        uint2 v1 = h2 ? im[k + 1] : make_uint2(0u, 0u);
        mov_3x3(v0, sm);
        mov_3x3(v1, sm);
    }
    for (unsigned k = threadIdx.x; k < nf; k += 256)
        fix_rect_diff(fi[k], sm, U, V, W);
    __syncthreads();
    if (threadIdx.x < 32) {
        int bx = threadIdx.x;
        unsigned u = 0, w = 0;
        for (int by = 0; by < 16; ++by) {
            int idx = (bx << 4) + by;
            u += U[idx]; w += W[idx];
            sm[idx] += u;
            V[idx] += w;
        }
    }
    __syncthreads();
    if (threadIdx.x < 16) {
        int by = threadIdx.x;
        unsigned tacc = 0;
        for (int bx = 0; bx < 32; ++bx) {
            int idx = (bx << 4) + by;
            tacc += V[idx];
            sm[idx] += tacc;
        }
    }
    __syncthreads();
    tile_reduce(sm, pm, baseX, baseY, out);
}

extern "C" void kernel_launch(void* const* d_in, const int* in_sizes, int n_in,
                              void* d_out, int out_size, void* d_ws, size_t ws_size,
                              hipStream_t stream) {
    const float* pos = (const float*)d_in[0];
    const float* xs = pos;
    const float* ys = pos + NTOT;
    const float* sxs = (const float*)d_in[1];
    const float* sys = (const float*)d_in[2];
    const unsigned char* pm = (const unsigned char*)d_in[5];
    float* out = (float*)d_out;

    // layout: counters + fixed-stride buckets + partials (36.03 MB; ws >= 60.85 MB)
    unsigned* gM = (unsigned*)d_ws;                                  // 8 KB
    unsigned* gF = gM + NTILES_;                                     // 8 KB
    uint2* itemsM = (uint2*)(gF + NTILES_);                          // 32 MB
    uint2* itemsF = itemsM + (size_t)NTILES_ * CAP_M;                // 4 MB
    float* partials = (float*)(itemsF + (size_t)NTILES_ * CAP_F);    // 4 KB

    void* args[] = { (void*)&xs, (void*)&ys, (void*)&sxs, (void*)&sys,
                     (void*)&gM, (void*)&gF, (void*)&itemsM, (void*)&itemsF,
                     (void*)&pm, (void*)&partials, (void*)&out };
    hipError_t e = hipLaunchCooperativeKernel((const void*)fused_k, dim3(FB_),
                                              dim3(FT_), args, 0, stream);
    if (e != hipSuccess) {
        // fallback: original 4-node path
        hipMemsetAsync(d_out, 0, 2 * sizeof(float), stream);
        hipMemsetAsync(gM, 0, 2 * NTILES_ * sizeof(unsigned), stream);
        bin_k<<<NB_, BT_, 0, stream>>>(xs, ys, sxs, sys, gM, gF, itemsM, itemsF);
        accum2_k<<<NTILES_, 256, 0, stream>>>(gM, gF, itemsM, itemsF, pm, out);
    }
}

// Round 3
// 160.890 us; speedup vs baseline: 2.0830x; 2.0830x over previous
//
#include <hip/hip_runtime.h>

#define NM_ 1500000
#define NT_ 100000
#define NF_ 1500000
#define NTOT (NM_ + NT_ + NF_)
#define NBY_ 1024
#define TDv 0.9f

#define NB_  512          /* binning grid blocks */
#define BT_  1024         /* binning threads/block */
#define NIT  6            /* nodes cached per thread: 6*512*1024 >= NTOT */
#define SHY_ 4
#define TSY_ 16
#define NTILY_ 64                 /* y-tiles */
#define NTILES_ 2048              /* 32 x-tiles x 64 y-tiles (32x16 bins) */
#define CAP_M 2048u               /* movable bucket stride (mean 1619, +10 sigma) */
#define CAP_F 256u                /* fixed-rect bucket stride (mean ~115, +13 sigma) */
#define QS 0.0009765625f          /* 1/1024 */
#define FXS 65536.0f              /* LDS fixed-point scale (2^16) */
#define FXSI 1.52587890625e-5f    /* 2^-16 */

// universal 8B item: tile-local fixed point
// w0 = xq(u6.10)<<16 | yq(u6.10)   (coords offset by +32; range [-32,32))
// w1 = sxq(u5.10)<<16 | syq(u5.10) (sizes up to 20.03 fit 15 bits)
__device__ inline uint2 pack_item(float xl, float yl, float sx, float sy) {
    unsigned xq = min((unsigned)__builtin_rintf((xl + 32.0f) * 1024.0f), 65535u);
    unsigned yq = min((unsigned)__builtin_rintf((yl + 32.0f) * 1024.0f), 65535u);
    unsigned sxq = (unsigned)__builtin_rintf(sx * 1024.0f);
    unsigned syq = (unsigned)__builtin_rintf(sy * 1024.0f);
    uint2 r; r.x = (xq << 16) | yq; r.y = (sxq << 16) | syq; return r;
}

// movable item: fully-unrolled 3x3 (span <= 3x3 always); zero-weight adds
// predicated off (typical footprint 2x2 -> ~5/9 adds are zero).
__device__ inline void mov_3x3(uint2 v, unsigned* sm) {
    float xl = (float)(v.x >> 16) * QS - 32.0f;
    float yl = (float)(v.x & 0xffffu) * QS - 32.0f;
    float sx = (float)(v.y >> 16) * QS;
    float sy = (float)(v.y & 0xffffu) * QS;
    float xh = xl + sx, yh = yl + sy;
    int bx0 = (int)floorf(xl), by0 = (int)floorf(yl);
    #pragma unroll
    for (int dx = 0; dx < 3; ++dx) {
        int bx = bx0 + dx;
        float ox = fmaxf(fminf(xh, (float)(bx + 1)) - fmaxf(xl, (float)bx), 0.0f) * FXS;
        bool okx = ((unsigned)bx < 32u);
        int bxc = min(max(bx, 0), 31);
        #pragma unroll
        for (int dy = 0; dy < 3; ++dy) {
            int by = by0 + dy;
            float oy = fmaxf(fminf(yh, (float)(by + 1)) - fmaxf(yl, (float)by), 0.0f);
            float w = (okx && ((unsigned)by < 16u)) ? ox * oy : 0.0f;
            int byc = min(max(by, 0), 15);
            if (w != 0.0f)
                atomicAdd(&sm[(bxc << 4) + byc], (unsigned)__float2uint_rn(w));
        }
    }
}

// fixed rect via separable difference maps: <=16 point adds instead of
// walking the O(area) footprint. Signed entries ride in u32 two's-complement.
// A zero item (all fields 0) is a no-op (all predicates false).
__device__ inline void fix_rect_diff(uint2 v, unsigned* S, unsigned* U,
                                     unsigned* V, unsigned* W) {
    float xl = (float)(v.x >> 16) * QS - 32.0f;
    float yl = (float)(v.x & 0xffffu) * QS - 32.0f;
    float sx = (float)(v.y >> 16) * QS;
    float sy = (float)(v.y & 0xffffu) * QS;
    float xh = xl + sx, yh = yl + sy;
    int xlo = (int)floorf(xl), xhi = (int)floorf(xh);
    int ylo = (int)floorf(yl), yhi = (int)floorf(yh);
    float ax = fminf(xh, (float)(xlo + 1)) - xl;
    float bx = xh - (float)xhi;
    float ay = fminf(yh, (float)(ylo + 1)) - yl;
    float by = yh - (float)yhi;
    int xs = max(xlo + 1, 0), xe = min(xhi - 1, 31);
    int ys = max(ylo + 1, 0), ye = min(yhi - 1, 15);
    bool runx = (xs <= xe), runy = (ys <= ye);
    bool c_xlo = ((unsigned)xlo < 32u), c_xhi = ((unsigned)xhi < 32u);
    bool c_ylo = ((unsigned)ylo < 16u), c_yhi = ((unsigned)yhi < 16u);
    const float SC = TDv * FXS;
    if (c_xlo && c_ylo) atomicAdd(&S[(xlo << 4) + ylo], (unsigned)__float2int_rn(ax * ay * SC));
    if (c_xlo && c_yhi) atomicAdd(&S[(xlo << 4) + yhi], (unsigned)__float2int_rn(ax * by * SC));
    if (c_xhi && c_ylo) atomicAdd(&S[(xhi << 4) + ylo], (unsigned)__float2int_rn(bx * ay * SC));
    if (c_xhi && c_yhi) atomicAdd(&S[(xhi << 4) + yhi], (unsigned)__float2int_rn(bx * by * SC));
    if (runy) {
        int iax = __float2int_rn(ax * SC), ibx = __float2int_rn(bx * SC);
        if (c_xlo) {
            atomicAdd(&U[(xlo << 4) + ys], (unsigned)iax);
            if (ye < 15) atomicAdd(&U[(xlo << 4) + ye + 1], (unsigned)(-iax));
        }
        if (c_xhi) {
            atomicAdd(&U[(xhi << 4) + ys], (unsigned)ibx);
            if (ye < 15) atomicAdd(&U[(xhi << 4) + ye + 1], (unsigned)(-ibx));
        }
    }
    if (runx) {
        int iay = __float2int_rn(ay * SC), iby = __float2int_rn(by * SC);
        if (c_ylo) {
            atomicAdd(&V[(xs << 4) + ylo], (unsigned)iay);
            if (xe < 31) atomicAdd(&V[((xe + 1) << 4) + ylo], (unsigned)(-iay));
        }
        if (c_yhi) {
            atomicAdd(&V[(xs << 4) + yhi], (unsigned)iby);
            if (xe < 31) atomicAdd(&V[((xe + 1) << 4) + yhi], (unsigned)(-iby));
        }
    }
    if (runx && runy) {
        const int iSC = 58982;   /* round(TDv * FXS) */
        atomicAdd(&W[(xs << 4) + ys], (unsigned)iSC);
        if (ye < 15) atomicAdd(&W[(xs << 4) + ye + 1], (unsigned)(-iSC));
        if (xe < 31) {
            atomicAdd(&W[((xe + 1) << 4) + ys], (unsigned)(-iSC));
            if (ye < 15) atomicAdd(&W[((xe + 1) << 4) + ye + 1], (unsigned)iSC);
        }
    }
}

// ============== fused binning: per-tile rect items for BOTH classes =========
__global__ __launch_bounds__(BT_) void
bin_k(const float* __restrict__ xs, const float* __restrict__ ys,
      const float* __restrict__ sxs, const float* __restrict__ sys,
      unsigned* __restrict__ gM, unsigned* __restrict__ gF,
      uint2* __restrict__ itemsM, uint2* __restrict__ itemsF) {
    __shared__ unsigned lhM[NTILES_], lhF[NTILES_];   // counts -> bucket bases
    __shared__ unsigned cM[NTILES_], cF[NTILES_];     // phase-2 cursors
    for (int j = threadIdx.x; j < NTILES_; j += BT_) { lhM[j] = 0u; lhF[j] = 0u; }
    __syncthreads();
    int t0 = blockIdx.x * BT_ + threadIdx.x;
    float cx[NIT], cy[NIT], csx[NIT], csy[NIT];
    bool val[NIT], fixc[NIT];
    #pragma unroll
    for (int k = 0; k < NIT; ++k) {
        int i = t0 + k * (NB_ * BT_);
        val[k] = (i < NTOT);
        int ii = val[k] ? i : 0;
        cx[k] = xs[ii]; cy[k] = ys[ii]; csx[k] = sxs[ii]; csy[k] = sys[ii];
        fixc[k] = (i >= NM_) && (i < NM_ + NT_);
    }
    // phase 1: per-tile LDS histogram
    #pragma unroll
    for (int k = 0; k < NIT; ++k) if (val[k]) {
        float xi = cx[k], yi = cy[k];
        int txa = (int)xi >> 5, txb = (int)(xi + csx[k]) >> 5;
        int tya = (int)yi >> SHY_, tyb = (int)(yi + csy[k]) >> SHY_;
        unsigned* lh = fixc[k] ? lhF : lhM;
        for (int tx = txa; tx <= txb; ++tx)
            for (int ty = tya; ty <= tyb; ++ty) atomicAdd(&lh[tx * NTILY_ + ty], 1u);
    }
    __syncthreads();
    // block base within each tile bucket via one global bump per (tile, block)
    for (int j = threadIdx.x; j < NTILES_; j += BT_) {
        unsigned c = lhM[j];
        lhM[j] = c ? atomicAdd(&gM[j], c) : 0u;
        cM[j] = 0u;
        c = lhF[j];
        lhF[j] = c ? atomicAdd(&gF[j], c) : 0u;
        cF[j] = 0u;
    }
    __syncthreads();
    // phase 2: emit one 8B rect item per (node, tile)
    #pragma unroll
    for (int k = 0; k < NIT; ++k) if (val[k]) {
        float xi = cx[k], yi = cy[k], sxi = csx[k], syi = csy[k];
        int txa = (int)xi >> 5, txb = (int)(xi + sxi) >> 5;
        int tya = (int)yi >> SHY_, tyb = (int)(yi + syi) >> SHY_;
        if (fixc[k]) {
            for (int tx = txa; tx <= txb; ++tx)
                for (int ty = tya; ty <= tyb; ++ty) {
                    int tl = tx * NTILY_ + ty;
                    unsigned r = lhF[tl] + atomicAdd(&cF[tl], 1u);
                    if (r < CAP_F)
                        itemsF[(size_t)tl * CAP_F + r] =
                            pack_item(xi - (float)(tx * 32), yi - (float)(ty * TSY_), sxi, syi);
                }
        } else {
            for (int tx = txa; tx <= txb; ++tx)
                for (int ty = tya; ty <= tyb; ++ty) {
                    int tl = tx * NTILY_ + ty;
                    unsigned r = lhM[tl] + atomicAdd(&cM[tl], 1u);
                    if (r < CAP_M)
                        itemsM[(size_t)tl * CAP_M + r] =
                            pack_item(xi - (float)(tx * 32), yi - (float)(ty * TSY_), sxi, syi);
                }
        }
    }
}

// ---------------------------------------------------------------- accum ----
// R3: tail writes per-block (S, M) with PLAIN STORES into partials[].
// R0/R1 ended with 2048 blocks x (atomicAdd + atomicMax) on the SAME global
// address -> serialized at the device coherence point (~60 us invariant to
// all in-kernel changes). reduce_k below does the final 2048 -> 1 reduce.
__global__ __launch_bounds__(256) void
accum2_k(const unsigned* __restrict__ gM, const unsigned* __restrict__ gF,
         const uint2* __restrict__ itemsM, const uint2* __restrict__ itemsF,
         const unsigned char* __restrict__ pm, float* __restrict__ partials) {
    __shared__ unsigned sm[512], U[512], V[512], W[512];
    int t = blockIdx.x;
    int baseX = (t >> 6) * 32, baseY = (t & 63) * TSY_;
    unsigned nm = min(gM[t], CAP_M), nf = min(gF[t], CAP_F);
    const uint2* im = itemsM + (size_t)t * CAP_M;
    const uint2* fi = itemsF + (size_t)t * CAP_F;

    // ---- issue all loads up front (independent -> high MLP) ----
    uint2 itv[8];
    #pragma unroll
    for (int j = 0; j < 4; ++j) {
        unsigned k = threadIdx.x * 2u + (unsigned)j * 512u;
        uint4 u = make_uint4(0u, 0u, 0u, 0u);
        if (k < nm) u = *(const uint4*)(im + k);       // 16B aligned: k even, im 16KB-aligned
        bool h2 = (k + 1u < nm);
        itv[2 * j].x = u.x;           itv[2 * j].y = u.y;
        itv[2 * j + 1].x = h2 ? u.z : 0u;
        itv[2 * j + 1].y = h2 ? u.w : 0u;
    }
    uint2 fv = make_uint2(0u, 0u);                     // zero item = no-op in fix_rect_diff
    if (threadIdx.x < nf) fv = fi[threadIdx.x];
    int j0 = threadIdx.x, j1 = threadIdx.x + 256;
    unsigned char p0 = pm[(size_t)(baseX + (j0 >> SHY_)) * NBY_ + baseY + (j0 & (TSY_ - 1))];
    unsigned char p1 = pm[(size_t)(baseX + (j1 >> SHY_)) * NBY_ + baseY + (j1 & (TSY_ - 1))];

    for (int j = threadIdx.x; j < 512; j += 256) { sm[j] = 0u; U[j] = 0u; V[j] = 0u; W[j] = 0u; }
    __syncthreads();

    // phase A: movable rects from registers
    #pragma unroll
    for (int j = 0; j < 8; ++j) mov_3x3(itv[j], sm);
    // phase B: fixed rects, per-lane difference-map scatter (O(1) per rect)
    fix_rect_diff(fv, sm, U, V, W);
    __syncthreads();

    // reconstruction pass 1: per-bx prefix along y; sm += Py(U); V += Py(W)
    if (threadIdx.x < 32) {
        int bx = threadIdx.x;
        unsigned u = 0, w = 0;
        for (int by = 0; by < 16; ++by) {
            int idx = (bx << 4) + by;
            u += U[idx]; w += W[idx];
            sm[idx] += u;
            V[idx] += w;
        }
    }
    __syncthreads();
    // pass 2: per-by prefix along x of (V + Py(W)) added into sm
    if (threadIdx.x < 16) {
        int by = threadIdx.x;
        unsigned tacc = 0;
        for (int bx = 0; bx < 32; ++bx) {
            int idx = (bx << 4) + by;
            tacc += V[idx];
            sm[idx] += tacc;
        }
    }
    __syncthreads();

    // tail: reduce 512 bins -> (S, M), plain store (NO global atomics)
    float d0 = (float)sm[j0] * FXSI;
    if (p0) d0 = TDv;
    float d1 = (float)sm[j1] * FXSI;
    if (p1) d1 = TDv;
    float acc = fmaxf(d0 - TDv, 0.0f) + fmaxf(d1 - TDv, 0.0f);
    float mx = fmaxf(d0, d1);
    int lane = threadIdx.x & 63, wv = threadIdx.x >> 6;
    for (int off2 = 32; off2 > 0; off2 >>= 1) {
        acc += __shfl_down(acc, off2, 64);
        mx = fmaxf(mx, __shfl_down(mx, off2, 64));
    }
    __shared__ float ssum[4], smax[4];
    if (lane == 0) { ssum[wv] = acc; smax[wv] = mx; }
    __syncthreads();
    if (threadIdx.x == 0) {
        float S = ssum[0], M = smax[0];
        for (int w2 = 1; w2 < 4; ++w2) { S += ssum[w2]; M = fmaxf(M, smax[w2]); }
        partials[2 * t] = S;
        partials[2 * t + 1] = M;
    }
}

// -------------------------------------------------------- final reduce ----
// single block: 2048 (S, M) pairs -> out[0..1]; also removes memset(out).
__global__ __launch_bounds__(1024) void
reduce_k(const float* __restrict__ partials, float* __restrict__ out) {
    int t = threadIdx.x;
    float S = partials[2 * t] + partials[2 * (t + 1024)];
    float M = fmaxf(partials[2 * t + 1], partials[2 * (t + 1024) + 1]);
    for (int off2 = 32; off2 > 0; off2 >>= 1) {
        S += __shfl_down(S, off2, 64);
        M = fmaxf(M, __shfl_down(M, off2, 64));
    }
    __shared__ float sS[16], sM[16];
    int lane = t & 63, wv = t >> 6;
    if (lane == 0) { sS[wv] = S; sM[wv] = M; }
    __syncthreads();
    if (t == 0) {
        float a = sS[0], b = sM[0];
        for (int w2 = 1; w2 < 16; ++w2) { a += sS[w2]; b = fmaxf(b, sM[w2]); }
        out[0] = a;           // density_cost
        out[1] = b;           // max_density (bin_area = 1)
    }
}

extern "C" void kernel_launch(void* const* d_in, const int* in_sizes, int n_in,
                              void* d_out, int out_size, void* d_ws, size_t ws_size,
                              hipStream_t stream) {
    const float* pos = (const float*)d_in[0];
    const float* xs = pos;
    const float* ys = pos + NTOT;
    const float* sxs = (const float*)d_in[1];
    const float* sys = (const float*)d_in[2];
    const unsigned char* pm = (const unsigned char*)d_in[5];
    float* out = (float*)d_out;

    // layout: counters + fixed-stride buckets + partials (36.05 MB; ws >= 60.85 MB)
    unsigned* gM = (unsigned*)d_ws;                                  // 8 KB
    unsigned* gF = gM + NTILES_;                                     // 8 KB
    uint2* itemsM = (uint2*)(gF + NTILES_);                          // 32 MB
    uint2* itemsF = itemsM + (size_t)NTILES_ * CAP_M;                // 4 MB
    float* partials = (float*)(itemsF + (size_t)NTILES_ * CAP_F);    // 16 KB

    hipMemsetAsync(gM, 0, 2 * NTILES_ * sizeof(unsigned), stream);
    bin_k<<<NB_, BT_, 0, stream>>>(xs, ys, sxs, sys, gM, gF, itemsM, itemsF);
    accum2_k<<<NTILES_, 256, 0, stream>>>(gM, gF, itemsM, itemsF, pm, partials);
    reduce_k<<<1, 1024, 0, stream>>>(partials, out);
}

// Round 4
// 152.217 us; speedup vs baseline: 2.2017x; 1.0570x over previous
//
#include <hip/hip_runtime.h>

#define NM_ 1500000
#define NT_ 100000
#define NF_ 1500000
#define NTOT (NM_ + NT_ + NF_)
#define NBY_ 1024
#define TDv 0.9f

#define NB_  512          /* binning grid blocks */
#define BT_  1024         /* binning threads/block */
#define NIT  6            /* nodes cached per thread: 6*512*1024 >= NTOT */
#define SHY_ 5            /* tile = 32x32 bins now */
#define TSY_ 32
#define NTILY_ 32                 /* y-tiles */
#define NTILES_ 1024              /* 32 x-tiles x 32 y-tiles (32x32 bins) */
#define CAP_M 4096u               /* movable bucket stride (mean ~3140, +17 sigma) */
#define CAP_F 512u                /* fixed-rect bucket stride (mean ~177, +25 sigma) */
#define QS 0.0009765625f          /* 1/1024 */
#define FXS 65536.0f              /* LDS fixed-point scale (2^16) */
#define FXSI 1.52587890625e-5f    /* 2^-16 */

// universal 8B item: tile-local fixed point
// w0 = xq(u6.10)<<16 | yq(u6.10)   (coords offset by +32; range [-32,32))
// w1 = sxq(u5.10)<<16 | syq(u5.10) (sizes up to 20.03 fit 15 bits)
// 32x32 tiles: node spans <= 2 tiles per dim (max size 20.03 < 32), so
// local coords stay in [-32, 32) -> same packing as before.
__device__ inline uint2 pack_item(float xl, float yl, float sx, float sy) {
    unsigned xq = min((unsigned)__builtin_rintf((xl + 32.0f) * 1024.0f), 65535u);
    unsigned yq = min((unsigned)__builtin_rintf((yl + 32.0f) * 1024.0f), 65535u);
    unsigned sxq = (unsigned)__builtin_rintf(sx * 1024.0f);
    unsigned syq = (unsigned)__builtin_rintf(sy * 1024.0f);
    uint2 r; r.x = (xq << 16) | yq; r.y = (sxq << 16) | syq; return r;
}

// movable item: fully-unrolled 3x3 (movable size <= ~2 -> span <= 3 bins);
// zero-weight adds predicated off. Bin index within 32x32 tile: (bx<<5)+by.
__device__ inline void mov_3x3(uint2 v, unsigned* sm) {
    float xl = (float)(v.x >> 16) * QS - 32.0f;
    float yl = (float)(v.x & 0xffffu) * QS - 32.0f;
    float sx = (float)(v.y >> 16) * QS;
    float sy = (float)(v.y & 0xffffu) * QS;
    float xh = xl + sx, yh = yl + sy;
    int bx0 = (int)floorf(xl), by0 = (int)floorf(yl);
    #pragma unroll
    for (int dx = 0; dx < 3; ++dx) {
        int bx = bx0 + dx;
        float ox = fmaxf(fminf(xh, (float)(bx + 1)) - fmaxf(xl, (float)bx), 0.0f) * FXS;
        bool okx = ((unsigned)bx < 32u);
        int bxc = min(max(bx, 0), 31);
        #pragma unroll
        for (int dy = 0; dy < 3; ++dy) {
            int by = by0 + dy;
            float oy = fmaxf(fminf(yh, (float)(by + 1)) - fmaxf(yl, (float)by), 0.0f);
            float w = (okx && ((unsigned)by < 32u)) ? ox * oy : 0.0f;
            int byc = min(max(by, 0), 31);
            if (w != 0.0f)
                atomicAdd(&sm[(bxc << 5) + byc], (unsigned)__float2uint_rn(w));
        }
    }
}

// fixed rect via separable difference maps: <=16 point adds instead of
// walking the O(area) footprint. Signed entries ride in u32 two's-complement.
// A zero item (all fields 0) is a no-op (all predicates false).
__device__ inline void fix_rect_diff(uint2 v, unsigned* S, unsigned* U,
                                     unsigned* V, unsigned* W) {
    float xl = (float)(v.x >> 16) * QS - 32.0f;
    float yl = (float)(v.x & 0xffffu) * QS - 32.0f;
    float sx = (float)(v.y >> 16) * QS;
    float sy = (float)(v.y & 0xffffu) * QS;
    float xh = xl + sx, yh = yl + sy;
    int xlo = (int)floorf(xl), xhi = (int)floorf(xh);
    int ylo = (int)floorf(yl), yhi = (int)floorf(yh);
    float ax = fminf(xh, (float)(xlo + 1)) - xl;
    float bx = xh - (float)xhi;
    float ay = fminf(yh, (float)(ylo + 1)) - yl;
    float by = yh - (float)yhi;
    int xs = max(xlo + 1, 0), xe = min(xhi - 1, 31);
    int ys = max(ylo + 1, 0), ye = min(yhi - 1, 31);
    bool runx = (xs <= xe), runy = (ys <= ye);
    bool c_xlo = ((unsigned)xlo < 32u), c_xhi = ((unsigned)xhi < 32u);
    bool c_ylo = ((unsigned)ylo < 32u), c_yhi = ((unsigned)yhi < 32u);
    const float SC = TDv * FXS;
    if (c_xlo && c_ylo) atomicAdd(&S[(xlo << 5) + ylo], (unsigned)__float2int_rn(ax * ay * SC));
    if (c_xlo && c_yhi) atomicAdd(&S[(xlo << 5) + yhi], (unsigned)__float2int_rn(ax * by * SC));
    if (c_xhi && c_ylo) atomicAdd(&S[(xhi << 5) + ylo], (unsigned)__float2int_rn(bx * ay * SC));
    if (c_xhi && c_yhi) atomicAdd(&S[(xhi << 5) + yhi], (unsigned)__float2int_rn(bx * by * SC));
    if (runy) {
        int iax = __float2int_rn(ax * SC), ibx = __float2int_rn(bx * SC);
        if (c_xlo) {
            atomicAdd(&U[(xlo << 5) + ys], (unsigned)iax);
            if (ye < 31) atomicAdd(&U[(xlo << 5) + ye + 1], (unsigned)(-iax));
        }
        if (c_xhi) {
            atomicAdd(&U[(xhi << 5) + ys], (unsigned)ibx);
            if (ye < 31) atomicAdd(&U[(xhi << 5) + ye + 1], (unsigned)(-ibx));
        }
    }
    if (runx) {
        int iay = __float2int_rn(ay * SC), iby = __float2int_rn(by * SC);
        if (c_ylo) {
            atomicAdd(&V[(xs << 5) + ylo], (unsigned)iay);
            if (xe < 31) atomicAdd(&V[((xe + 1) << 5) + ylo], (unsigned)(-iay));
        }
        if (c_yhi) {
            atomicAdd(&V[(xs << 5) + yhi], (unsigned)iby);
            if (xe < 31) atomicAdd(&V[((xe + 1) << 5) + yhi], (unsigned)(-iby));
        }
    }
    if (runx && runy) {
        const int iSC = 58982;   /* round(TDv * FXS) */
        atomicAdd(&W[(xs << 5) + ys], (unsigned)iSC);
        if (ye < 31) atomicAdd(&W[(xs << 5) + ye + 1], (unsigned)(-iSC));
        if (xe < 31) {
            atomicAdd(&W[((xe + 1) << 5) + ys], (unsigned)(-iSC));
            if (ye < 31) atomicAdd(&W[((xe + 1) << 5) + ye + 1], (unsigned)iSC);
        }
    }
}

// ============== fused binning: per-tile rect items for BOTH classes =========
// launch_bounds min-waves=4 -> 128-VGPR budget: kills any scratch spill of
// the 24-float node cache (R3 showed VGPR_Count=28, the R2 spill pathology).
__global__ __launch_bounds__(BT_, 4) void
bin_k(const float* __restrict__ xs, const float* __restrict__ ys,
      const float* __restrict__ sxs, const float* __restrict__ sys,
      unsigned* __restrict__ gM, unsigned* __restrict__ gF,
      uint2* __restrict__ itemsM, uint2* __restrict__ itemsF) {
    __shared__ unsigned lhM[NTILES_], lhF[NTILES_];   // counts -> bucket bases
    __shared__ unsigned cM[NTILES_], cF[NTILES_];     // phase-2 cursors
    for (int j = threadIdx.x; j < NTILES_; j += BT_) { lhM[j] = 0u; lhF[j] = 0u; }
    __syncthreads();
    int t0 = blockIdx.x * BT_ + threadIdx.x;
    float cx[NIT], cy[NIT], csx[NIT], csy[NIT];
    bool val[NIT], fixc[NIT];
    #pragma unroll
    for (int k = 0; k < NIT; ++k) {
        int i = t0 + k * (NB_ * BT_);
        val[k] = (i < NTOT);
        int ii = val[k] ? i : 0;
        cx[k] = xs[ii]; cy[k] = ys[ii]; csx[k] = sxs[ii]; csy[k] = sys[ii];
        fixc[k] = (i >= NM_) && (i < NM_ + NT_);
    }
    // phase 1: per-tile LDS histogram
    #pragma unroll
    for (int k = 0; k < NIT; ++k) if (val[k]) {
        float xi = cx[k], yi = cy[k];
        int txa = (int)xi >> 5, txb = (int)(xi + csx[k]) >> 5;
        int tya = (int)yi >> SHY_, tyb = (int)(yi + csy[k]) >> SHY_;
        unsigned* lh = fixc[k] ? lhF : lhM;
        for (int tx = txa; tx <= txb; ++tx)
            for (int ty = tya; ty <= tyb; ++ty) atomicAdd(&lh[tx * NTILY_ + ty], 1u);
    }
    __syncthreads();
    // block base within each tile bucket via one global bump per (tile, block)
    for (int j = threadIdx.x; j < NTILES_; j += BT_) {
        unsigned c = lhM[j];
        lhM[j] = c ? atomicAdd(&gM[j], c) : 0u;
        cM[j] = 0u;
        c = lhF[j];
        lhF[j] = c ? atomicAdd(&gF[j], c) : 0u;
        cF[j] = 0u;
    }
    __syncthreads();
    // phase 2: emit one 8B rect item per (node, tile); a block's items per
    // tile land in a contiguous run (base + local cursor) -> ~6-item runs
    // at 32x32 tiles (48B of a 64B line vs 24B at the old 32x16 tiles).
    #pragma unroll
    for (int k = 0; k < NIT; ++k) if (val[k]) {
        float xi = cx[k], yi = cy[k], sxi = csx[k], syi = csy[k];
        int txa = (int)xi >> 5, txb = (int)(xi + sxi) >> 5;
        int tya = (int)yi >> SHY_, tyb = (int)(yi + syi) >> SHY_;
        if (fixc[k]) {
            for (int tx = txa; tx <= txb; ++tx)
                for (int ty = tya; ty <= tyb; ++ty) {
                    int tl = tx * NTILY_ + ty;
                    unsigned r = lhF[tl] + atomicAdd(&cF[tl], 1u);
                    if (r < CAP_F)
                        itemsF[(size_t)tl * CAP_F + r] =
                            pack_item(xi - (float)(tx * 32), yi - (float)(ty * TSY_), sxi, syi);
                }
        } else {
            for (int tx = txa; tx <= txb; ++tx)
                for (int ty = tya; ty <= tyb; ++ty) {
                    int tl = tx * NTILY_ + ty;
                    unsigned r = lhM[tl] + atomicAdd(&cM[tl], 1u);
                    if (r < CAP_M)
                        itemsM[(size_t)tl * CAP_M + r] =
                            pack_item(xi - (float)(tx * 32), yi - (float)(ty * TSY_), sxi, syi);
                }
        }
    }
}

// ---------------------------------------------------------------- accum ----
// 1024 blocks x 256 threads, 16KB LDS -> 4 blocks/CU: whole grid co-resident.
// Tail: plain stores to partials[] (no global atomics -- R3's 3x win).
__global__ __launch_bounds__(256, 4) void
accum2_k(const unsigned* __restrict__ gM, const unsigned* __restrict__ gF,
         const uint2* __restrict__ itemsM, const uint2* __restrict__ itemsF,
         const unsigned char* __restrict__ pm, float* __restrict__ partials) {
    __shared__ unsigned sm[1024], U[1024], V[1024], W[1024];
    int t = blockIdx.x;
    int baseX = (t >> 5) * 32, baseY = (t & 31) * TSY_;
    unsigned nm = min(gM[t], CAP_M), nf = min(gF[t], CAP_F);
    const uint2* im = itemsM + (size_t)t * CAP_M;
    const uint2* fi = itemsF + (size_t)t * CAP_F;

    // ---- issue all loads up front (independent -> high MLP) ----
    uint2 itv[16];
    #pragma unroll
    for (int j = 0; j < 8; ++j) {
        unsigned k = threadIdx.x * 2u + (unsigned)j * 512u;
        uint4 u = make_uint4(0u, 0u, 0u, 0u);
        if (k < nm) u = *(const uint4*)(im + k);       // 16B aligned: k even, im 32KB-aligned
        bool h2 = (k + 1u < nm);
        itv[2 * j].x = u.x;           itv[2 * j].y = u.y;
        itv[2 * j + 1].x = h2 ? u.z : 0u;
        itv[2 * j + 1].y = h2 ? u.w : 0u;
    }
    uint2 fv0 = make_uint2(0u, 0u), fv1 = make_uint2(0u, 0u);  // zero item = no-op
    {
        unsigned k = threadIdx.x * 2u;
        uint4 u = make_uint4(0u, 0u, 0u, 0u);
        if (k < nf) u = *(const uint4*)(fi + k);       // nf <= 512 = 2*256
        fv0.x = u.x; fv0.y = u.y;
        if (k + 1u < nf) { fv1.x = u.z; fv1.y = u.w; }
    }
    int j0 = threadIdx.x, j1 = j0 + 256, j2 = j0 + 512, j3 = j0 + 768;
    unsigned char p0 = pm[(size_t)(baseX + (j0 >> 5)) * NBY_ + baseY + (j0 & 31)];
    unsigned char p1 = pm[(size_t)(baseX + (j1 >> 5)) * NBY_ + baseY + (j1 & 31)];
    unsigned char p2 = pm[(size_t)(baseX + (j2 >> 5)) * NBY_ + baseY + (j2 & 31)];
    unsigned char p3 = pm[(size_t)(baseX + (j3 >> 5)) * NBY_ + baseY + (j3 & 31)];

    for (int j = threadIdx.x; j < 1024; j += 256) { sm[j] = 0u; U[j] = 0u; V[j] = 0u; W[j] = 0u; }
    __syncthreads();

    // phase A: movable rects from registers
    #pragma unroll
    for (int j = 0; j < 16; ++j) mov_3x3(itv[j], sm);
    // phase B: fixed rects, per-lane difference-map scatter (O(1) per rect)
    fix_rect_diff(fv0, sm, U, V, W);
    fix_rect_diff(fv1, sm, U, V, W);
    __syncthreads();

    // reconstruction pass 1: per-bx prefix along y; sm += Py(U); V += Py(W)
    if (threadIdx.x < 32) {
        int bx = threadIdx.x;
        unsigned u = 0, w = 0;
        for (int by = 0; by < 32; ++by) {
            int idx = (bx << 5) + by;
            u += U[idx]; w += W[idx];
            sm[idx] += u;
            V[idx] += w;
        }
    }
    __syncthreads();
    // pass 2: per-by prefix along x of (V + Py(W)) added into sm
    if (threadIdx.x < 32) {
        int by = threadIdx.x;
        unsigned tacc = 0;
        for (int bx = 0; bx < 32; ++bx) {
            int idx = (bx << 5) + by;
            tacc += V[idx];
            sm[idx] += tacc;
        }
    }
    __syncthreads();

    // tail: reduce 1024 bins -> (S, M), plain store (NO global atomics)
    float d0 = (float)sm[j0] * FXSI;
    if (p0) d0 = TDv;
    float d1 = (float)sm[j1] * FXSI;
    if (p1) d1 = TDv;
    float d2 = (float)sm[j2] * FXSI;
    if (p2) d2 = TDv;
    float d3 = (float)sm[j3] * FXSI;
    if (p3) d3 = TDv;
    float acc = fmaxf(d0 - TDv, 0.0f) + fmaxf(d1 - TDv, 0.0f)
              + fmaxf(d2 - TDv, 0.0f) + fmaxf(d3 - TDv, 0.0f);
    float mx = fmaxf(fmaxf(d0, d1), fmaxf(d2, d3));
    int lane = threadIdx.x & 63, wv = threadIdx.x >> 6;
    for (int off2 = 32; off2 > 0; off2 >>= 1) {
        acc += __shfl_down(acc, off2, 64);
        mx = fmaxf(mx, __shfl_down(mx, off2, 64));
    }
    __shared__ float ssum[4], smax[4];
    if (lane == 0) { ssum[wv] = acc; smax[wv] = mx; }
    __syncthreads();
    if (threadIdx.x == 0) {
        float S = ssum[0], M = smax[0];
        for (int w2 = 1; w2 < 4; ++w2) { S += ssum[w2]; M = fmaxf(M, smax[w2]); }
        partials[2 * t] = S;
        partials[2 * t + 1] = M;
    }
}

// -------------------------------------------------------- final reduce ----
// single block: 1024 (S, M) pairs -> out[0..1]; also removes memset(out).
__global__ __launch_bounds__(1024) void
reduce_k(const float* __restrict__ partials, float* __restrict__ out) {
    int t = threadIdx.x;
    float S = partials[2 * t];
    float M = partials[2 * t + 1];
    for (int off2 = 32; off2 > 0; off2 >>= 1) {
        S += __shfl_down(S, off2, 64);
        M = fmaxf(M, __shfl_down(M, off2, 64));
    }
    __shared__ float sS[16], sM[16];
    int lane = t & 63, wv = t >> 6;
    if (lane == 0) { sS[wv] = S; sM[wv] = M; }
    __syncthreads();
    if (t == 0) {
        float a = sS[0], b = sM[0];
        for (int w2 = 1; w2 < 16; ++w2) { a += sS[w2]; b = fmaxf(b, sM[w2]); }
        out[0] = a;           // density_cost
        out[1] = b;           // max_density (bin_area = 1)
    }
}

extern "C" void kernel_launch(void* const* d_in, const int* in_sizes, int n_in,
                              void* d_out, int out_size, void* d_ws, size_t ws_size,
                              hipStream_t stream) {
    const float* pos = (const float*)d_in[0];
    const float* xs = pos;
    const float* ys = pos + NTOT;
    const float* sxs = (const float*)d_in[1];
    const float* sys = (const float*)d_in[2];
    const unsigned char* pm = (const unsigned char*)d_in[5];
    float* out = (float*)d_out;

    // layout: counters + fixed-stride buckets + partials (36.02 MB; ws >= 60.85 MB)
    unsigned* gM = (unsigned*)d_ws;                                  // 4 KB
    unsigned* gF = gM + NTILES_;                                     // 4 KB
    uint2* itemsM = (uint2*)(gF + NTILES_);                          // 32 MB
    uint2* itemsF = itemsM + (size_t)NTILES_ * CAP_M;                // 4 MB
    float* partials = (float*)(itemsF + (size_t)NTILES_ * CAP_F);    // 8 KB

    hipMemsetAsync(gM, 0, 2 * NTILES_ * sizeof(unsigned), stream);
    bin_k<<<NB_, BT_, 0, stream>>>(xs, ys, sxs, sys, gM, gF, itemsM, itemsF);
    accum2_k<<<NTILES_, 256, 0, stream>>>(gM, gF, itemsM, itemsF, pm, partials);
    reduce_k<<<1, 1024, 0, stream>>>(partials, out);
}